// Round 1
// baseline (295.458 us; speedup 1.0000x reference)
//
#include <hip/hip_runtime.h>
#include <math.h>

#define NN 4096
#define NE 16384
#define NG 64

// ---- ws layout (float offsets) ----
#define OFF_DEG   0         // 4096
#define OFF_H1    4096      // 4096*32
#define OFF_H2    135168    // 4096*64
#define OFF_H3    397312    // 4096*128
#define OFF_ST1   921600    // 64
#define OFF_ST2   921664    // 128
#define OFF_ST3   921792    // 256
#define OFF_POOL  922048    // 64*128
#define OFF_WC1   930240    // 16*288  = 4608
#define OFF_WC2   934848    // 32*576  = 18432
#define OFF_WC3   953280    // 64*1152 = 73728
#define OFF_Y     1027008   // 4096*1152 = 4718592 (reused across layers)
#define ZERO_FLOATS 930240  // zero deg/h/stats/pool only

// ---------------- prep: build Wcat (We + be as 9th filter) + degree ----------------
__device__ __forceinline__ void tr_wcat(const float* We, const float* be,
                                        float* Wcat, int CIN, int COUT, int t) {
    int nine = 9 * COUT;
    int i = t / nine; int r = t - i * nine;
    int f = r / COUT; int o = r - f * COUT;
    Wcat[t] = (f < 8) ? We[f * CIN * COUT + o * CIN + i] : be[o * CIN + i];
}

__global__ __launch_bounds__(256) void k_prep(
    const float* __restrict__ We1, const float* __restrict__ be1,
    const float* __restrict__ We2, const float* __restrict__ be2,
    const float* __restrict__ We3, const float* __restrict__ be3,
    const int* __restrict__ ei, float* __restrict__ ws)
{
    int t = blockIdx.x * 256 + threadIdx.x;
    if (t < 4608)  { tr_wcat(We1, be1, ws + OFF_WC1, 16, 32, t); return; }
    t -= 4608;
    if (t < 18432) { tr_wcat(We2, be2, ws + OFF_WC2, 32, 64, t); return; }
    t -= 18432;
    if (t < 73728) { tr_wcat(We3, be3, ws + OFF_WC3, 64, 128, t); return; }
    t -= 73728;
    if (t < NE)    { atomicAdd(&ws[OFF_DEG + ei[t]], 1.0f); }
}

// ---------------- proj GEMM: Y[n, col] = norm[n] * sum_i bnp(A[n,i]) * B[i,col] ----------------
// BM=64, BN=64, 256 threads, 4x4 per thread, K fully staged in LDS.
// BN=true: apply batchnorm(st/g/b) + PReLU(a) to A elements on load (per input-channel i).
template<int K, bool BN>
__global__ __launch_bounds__(256) void k_proj(
    const float* __restrict__ A,    // [4096, K]   (pre-BN h of previous layer, or x)
    const float* __restrict__ B,    // [K, Ncols]
    const float* __restrict__ deg,
    float* __restrict__ Y, int Ncols,
    const float* __restrict__ st, const float* __restrict__ g,
    const float* __restrict__ b, const float* __restrict__ a)
{
    __shared__ float sA[K][68];   // sA[i][m] (transposed A tile)
    __shared__ float sB[K][68];
    __shared__ float sS[K];
    __shared__ float sT[K];
    __shared__ float sAl;
    const int tid = threadIdx.x;
    const int m0 = blockIdx.x * 64;
    const int n0 = blockIdx.y * 64;

    if constexpr (BN) {
        if (tid < K) {
            float mean = st[tid] * (1.f / NN);
            float var  = st[K + tid] * (1.f / NN) - mean * mean;
            var = fmaxf(var, 0.f);
            float inv = rsqrtf(var + 1e-5f);
            float s = inv * g[tid];
            sS[tid] = s;
            sT[tid] = b[tid] - mean * s;
        }
        if (tid == 0) sAl = a[0];
    }
    __syncthreads();
    float al = 0.f;
    if constexpr (BN) al = sAl;

    for (int t = tid; t < 64 * K; t += 256) {
        int m = t / K, i = t - m * K;
        float v = A[(m0 + m) * K + i];
        if constexpr (BN) {
            v = fmaf(v, sS[i], sT[i]);
            v = v >= 0.f ? v : al * v;
        }
        sA[i][m] = v;
    }
    for (int t = tid; t < 64 * K; t += 256) {
        int i = t / 64, n = t - i * 64;
        int col = n0 + n;
        sB[i][n] = (col < Ncols) ? B[i * Ncols + col] : 0.f;
    }
    __syncthreads();

    const int tn = tid % 16, tm = tid / 16;
    float acc[4][4] = {{0.f}};
#pragma unroll 8
    for (int i = 0; i < K; ++i) {
        float4 av = *(const float4*)&sA[i][tm * 4];
        float4 bv = *(const float4*)&sB[i][tn * 4];
        acc[0][0] += av.x * bv.x; acc[0][1] += av.x * bv.y; acc[0][2] += av.x * bv.z; acc[0][3] += av.x * bv.w;
        acc[1][0] += av.y * bv.x; acc[1][1] += av.y * bv.y; acc[1][2] += av.y * bv.z; acc[1][3] += av.y * bv.w;
        acc[2][0] += av.z * bv.x; acc[2][1] += av.z * bv.y; acc[2][2] += av.z * bv.z; acc[2][3] += av.z * bv.w;
        acc[3][0] += av.w * bv.x; acc[3][1] += av.w * bv.y; acc[3][2] += av.w * bv.z; acc[3][3] += av.w * bv.w;
    }

#pragma unroll
    for (int mm = 0; mm < 4; ++mm) {
        int m = m0 + tm * 4 + mm;
        float d = deg[m];
        float nrm = d > 0.f ? 1.f / d : 0.f;
#pragma unroll
        for (int nn = 0; nn < 4; ++nn) {
            int col = n0 + tn * 4 + nn;
            if (col < Ncols) Y[(size_t)m * Ncols + col] = acc[mm][nn] * nrm;
        }
    }
}

// ---------------- per-edge gather: h[dst,4q..] += sum_f ea'[e,f] * Y[src, f*COUT+4q..] ----------------
// float4 per thread: COUT/4 threads per edge.
template<int COUT>
__global__ __launch_bounds__(256) void k_egather(
    const float* __restrict__ Y, const float* __restrict__ eattr,
    const int* __restrict__ ei, float* __restrict__ h)
{
    constexpr int TPE = COUT / 4;
    int idx = blockIdx.x * 256 + threadIdx.x;
    int e = idx / TPE;
    int q = idx - e * TPE;
    int src = ei[e], dst = ei[NE + e];
    const float4* y4 = (const float4*)(Y + (size_t)src * (9 * COUT));
    const float4* ea4 = (const float4*)(eattr + e * 8);
    float4 ea0 = ea4[0], ea1 = ea4[1];
    float4 acc = y4[8 * TPE + q];     // be-term, ea' = 1
#define FMA4(s, v) { float4 _t = (v); acc.x += (s)*_t.x; acc.y += (s)*_t.y; acc.z += (s)*_t.z; acc.w += (s)*_t.w; }
    FMA4(ea0.x, y4[0 * TPE + q]);
    FMA4(ea0.y, y4[1 * TPE + q]);
    FMA4(ea0.z, y4[2 * TPE + q]);
    FMA4(ea0.w, y4[3 * TPE + q]);
    FMA4(ea1.x, y4[4 * TPE + q]);
    FMA4(ea1.y, y4[5 * TPE + q]);
    FMA4(ea1.z, y4[6 * TPE + q]);
    FMA4(ea1.w, y4[7 * TPE + q]);
#undef FMA4
    float* hp = h + (size_t)dst * COUT + 4 * q;
    atomicAdd(hp + 0, acc.x);
    atomicAdd(hp + 1, acc.y);
    atomicAdd(hp + 2, acc.z);
    atomicAdd(hp + 3, acc.w);
}

// ---------------- node: residual + bias, accumulate BN stats ----------------
// BN=true: xin is pre-BN h of previous layer -> apply bn(st_in/g/b)+PReLU(a) on load.
template<int CIN, int COUT, int KN, bool BN>
__global__ __launch_bounds__(256) void k_node(
    const float* __restrict__ xin, const float* __restrict__ Wr,
    const float* __restrict__ br, const float* __restrict__ bias,
    float* __restrict__ h, float* __restrict__ st_out,
    const float* __restrict__ st_in, const float* __restrict__ g,
    const float* __restrict__ b, const float* __restrict__ a)
{
    constexpr int NL = 256 / COUT;
    constexpr int NB = NL * KN;
    constexpr int CINP = CIN | 1;
    __shared__ float sWr[CIN * COUT];
    __shared__ float sX[NB * CINP];
    __shared__ float sred[256];
    __shared__ float sS[CIN];
    __shared__ float sT[CIN];
    __shared__ float sAl;
    const int tid = threadIdx.x;
    const int nbase = blockIdx.x * NB;

    if constexpr (BN) {
        if (tid < CIN) {
            float mean = st_in[tid] * (1.f / NN);
            float var  = st_in[CIN + tid] * (1.f / NN) - mean * mean;
            var = fmaxf(var, 0.f);
            float inv = rsqrtf(var + 1e-5f);
            float s = inv * g[tid];
            sS[tid] = s;
            sT[tid] = b[tid] - mean * s;
        }
        if (tid == 0) sAl = a[0];
    }
    for (int t = tid; t < CIN * COUT; t += 256) sWr[t] = Wr[t];
    __syncthreads();
    float al = 0.f;
    if constexpr (BN) al = sAl;

    for (int t = tid; t < NB * CIN; t += 256) {
        int r = t / CIN, i = t - r * CIN;
        float v = xin[(nbase + r) * CIN + i];
        if constexpr (BN) {
            v = fmaf(v, sS[i], sT[i]);
            v = v >= 0.f ? v : al * v;
        }
        sX[r * CINP + i] = v;
    }
    __syncthreads();

    const int o = tid % COUT;
    const int nl = tid / COUT;
    const float addc = bias[o] + br[o];
    float sum = 0.f, sumsq = 0.f;
    for (int k = 0; k < KN; ++k) {
        int r = nl * KN + k;
        float acc = addc;
        for (int i = 0; i < CIN; ++i)
            acc += sX[r * CINP + i] * sWr[i * COUT + o];
        int gi = (nbase + r) * COUT + o;
        float hv = h[gi] + acc;
        h[gi] = hv;
        sum += hv; sumsq += hv * hv;
    }
    sred[tid] = sum;
    __syncthreads();
    if (tid < COUT) {
        float s = 0.f;
        for (int g2 = 0; g2 < NL; ++g2) s += sred[g2 * COUT + tid];
        atomicAdd(&st_out[tid], s);
    }
    __syncthreads();
    sred[tid] = sumsq;
    __syncthreads();
    if (tid < COUT) {
        float s = 0.f;
        for (int g2 = 0; g2 < NL; ++g2) s += sred[g2 * COUT + tid];
        atomicAdd(&st_out[COUT + tid], s);
    }
}

// ---------------- gated pooling (applies BN3+PReLU3 on h3 load) ----------------
__global__ __launch_bounds__(256) void k_pool(
    const float* __restrict__ h3, const int* __restrict__ batch,
    const float* __restrict__ Wi, const float* __restrict__ bi,
    const float* __restrict__ Wj, const float* __restrict__ bj,
    float* __restrict__ pooled,
    const float* __restrict__ st, const float* __restrict__ g,
    const float* __restrict__ b, const float* __restrict__ a)
{
    constexpr int KN = 8, NB = 16;
    __shared__ float sH[NB * 128];
    __shared__ int sB[NB];
    __shared__ float sS[128];
    __shared__ float sT[128];
    __shared__ float sAl;
    const int tid = threadIdx.x;
    const int nbase = blockIdx.x * NB;

    if (tid < 128) {
        float mean = st[tid] * (1.f / NN);
        float var  = st[128 + tid] * (1.f / NN) - mean * mean;
        var = fmaxf(var, 0.f);
        float inv = rsqrtf(var + 1e-5f);
        float s = inv * g[tid];
        sS[tid] = s;
        sT[tid] = b[tid] - mean * s;
    }
    if (tid == 0) sAl = a[0];
    __syncthreads();
    const float al = sAl;

    for (int t = tid; t < NB * 128; t += 256) {
        int c = t & 127;
        float v = h3[nbase * 128 + t];
        v = fmaf(v, sS[c], sT[c]);
        v = v >= 0.f ? v : al * v;
        sH[t] = v;
    }
    if (tid < NB) sB[tid] = batch[nbase + tid];
    __syncthreads();

    const int o = tid % 128, nl = tid / 128;
    float gacc[KN], facc[KN];
#pragma unroll
    for (int k = 0; k < KN; ++k) { gacc[k] = 0.f; facc[k] = 0.f; }
    for (int i = 0; i < 128; ++i) {
        float wi = Wi[i * 128 + o], wj = Wj[i * 128 + o];
#pragma unroll
        for (int k = 0; k < KN; ++k) {
            float hv = sH[(nl * KN + k) * 128 + i];
            gacc[k] += hv * wi;
            facc[k] += hv * wj;
        }
    }
    float bio = bi[o], bjo = bj[o];
#pragma unroll
    for (int k = 0; k < KN; ++k) {
        int r = nl * KN + k;
        float gate = 1.f / (1.f + expf(-(gacc[k] + bio)));
        float feat = tanhf(facc[k] + bjo);
        atomicAdd(&pooled[sB[r] * 128 + o], gate * feat);
    }
}

// ---------------- final: tanh(pooled) @ Wfc + bfc, split halves ----------------
__global__ __launch_bounds__(256) void k_final(
    const float* __restrict__ pooled, const float* __restrict__ Wfc,
    const float* __restrict__ bfc, float* __restrict__ out)
{
    __shared__ float sP[128];
    const int g = blockIdx.x, c = threadIdx.x;
    if (c < 128) sP[c] = tanhf(pooled[g * 128 + c]);
    __syncthreads();
    float z = bfc[c];
    for (int i = 0; i < 128; ++i) z += sP[i] * Wfc[i * 256 + c];
    int oidx = (c < 128) ? (g * 128 + c) : (NG * 128 + g * 128 + (c - 128));
    out[oidx] = z;
}

extern "C" void kernel_launch(void* const* d_in, const int* in_sizes, int n_in,
                              void* d_out, int out_size, void* d_ws, size_t ws_size,
                              hipStream_t stream)
{
    (void)in_sizes; (void)n_in; (void)out_size; (void)ws_size;
    const float* x     = (const float*)d_in[0];
    const float* eattr = (const float*)d_in[1];
    const int*   ei    = (const int*)d_in[2];
    const int*   batch = (const int*)d_in[3];
    const float* We1 = (const float*)d_in[4];
    const float* be1 = (const float*)d_in[5];
    const float* bias1 = (const float*)d_in[6];
    const float* Wr1 = (const float*)d_in[7];
    const float* br1 = (const float*)d_in[8];
    const float* bg1 = (const float*)d_in[9];
    const float* bb1 = (const float*)d_in[10];
    const float* a1  = (const float*)d_in[11];
    const float* We2 = (const float*)d_in[12];
    const float* be2 = (const float*)d_in[13];
    const float* bias2 = (const float*)d_in[14];
    const float* Wr2 = (const float*)d_in[15];
    const float* br2 = (const float*)d_in[16];
    const float* bg2 = (const float*)d_in[17];
    const float* bb2 = (const float*)d_in[18];
    const float* a2  = (const float*)d_in[19];
    const float* We3 = (const float*)d_in[20];
    const float* be3 = (const float*)d_in[21];
    const float* bias3 = (const float*)d_in[22];
    const float* Wr3 = (const float*)d_in[23];
    const float* br3 = (const float*)d_in[24];
    const float* bg3 = (const float*)d_in[25];
    const float* bb3 = (const float*)d_in[26];
    const float* a3  = (const float*)d_in[27];
    const float* Wi  = (const float*)d_in[28];
    const float* bi  = (const float*)d_in[29];
    const float* Wj  = (const float*)d_in[30];
    const float* bj  = (const float*)d_in[31];
    const float* Wfc = (const float*)d_in[32];
    const float* bfc = (const float*)d_in[33];
    float* ws  = (float*)d_ws;
    float* out = (float*)d_out;

    hipMemsetAsync(d_ws, 0, (size_t)ZERO_FLOATS * sizeof(float), stream);
    k_prep<<<442, 256, 0, stream>>>(We1, be1, We2, be2, We3, be3, ei, ws);

    // layer 1: cin=16, cout=32, Ncols=288  (no BN on input x)
    k_proj<16, false><<<dim3(64, 5), 256, 0, stream>>>(
        x, ws + OFF_WC1, ws + OFF_DEG, ws + OFF_Y, 288,
        nullptr, nullptr, nullptr, nullptr);
    k_egather<32><<<NE * 8 / 256, 256, 0, stream>>>(ws + OFF_Y, eattr, ei, ws + OFF_H1);
    k_node<16, 32, 2, false><<<NN / 16, 256, 0, stream>>>(
        x, Wr1, br1, bias1, ws + OFF_H1, ws + OFF_ST1,
        nullptr, nullptr, nullptr, nullptr);

    // layer 2: cin=32, cout=64, Ncols=576  (BN1+PReLU1 folded into loads of h1)
    k_proj<32, true><<<dim3(64, 9), 256, 0, stream>>>(
        ws + OFF_H1, ws + OFF_WC2, ws + OFF_DEG, ws + OFF_Y, 576,
        ws + OFF_ST1, bg1, bb1, a1);
    k_egather<64><<<NE * 16 / 256, 256, 0, stream>>>(ws + OFF_Y, eattr, ei, ws + OFF_H2);
    k_node<32, 64, 4, true><<<NN / 16, 256, 0, stream>>>(
        ws + OFF_H1, Wr2, br2, bias2, ws + OFF_H2, ws + OFF_ST2,
        ws + OFF_ST1, bg1, bb1, a1);

    // layer 3: cin=64, cout=128, Ncols=1152  (BN2+PReLU2 folded)
    k_proj<64, true><<<dim3(64, 18), 256, 0, stream>>>(
        ws + OFF_H2, ws + OFF_WC3, ws + OFF_DEG, ws + OFF_Y, 1152,
        ws + OFF_ST2, bg2, bb2, a2);
    k_egather<128><<<NE * 32 / 256, 256, 0, stream>>>(ws + OFF_Y, eattr, ei, ws + OFF_H3);
    k_node<64, 128, 8, true><<<NN / 16, 256, 0, stream>>>(
        ws + OFF_H2, Wr3, br3, bias3, ws + OFF_H3, ws + OFF_ST3,
        ws + OFF_ST2, bg2, bb2, a2);

    // pooling (BN3+PReLU3 folded) + head
    k_pool<<<NN / 16, 256, 0, stream>>>(ws + OFF_H3, batch, Wi, bi, Wj, bj, ws + OFF_POOL,
                                        ws + OFF_ST3, bg3, bb3, a3);
    k_final<<<NG, 256, 0, stream>>>(ws + OFF_POOL, Wfc, bfc, out);
}